// Round 1
// baseline (602.795 us; speedup 1.0000x reference)
//
#include <hip/hip_runtime.h>
#include <hip/hip_bf16.h>

#define N_NODES 10000
#define D_FEAT  128
#define BATCH   8192
#define K_NEIGH 25

// One block per batch element. 128 threads = 2 waves.
// Phase 1: threads 0..24 gather w[k] = adj[row,col] + feat_sims[row,col] into LDS.
// Phase 2: thread d accumulates sum_k w[k] * feat[idx[k]][d]; per-k the 128
//          lanes read one contiguous 512B feat row (coalesced, L2-resident).
__global__ __launch_bounds__(D_FEAT) void mean_agg_kernel(
    const int* __restrict__ nodes,      // [BATCH]
    const int* __restrict__ neigh_idx,  // [BATCH, K]
    const float* __restrict__ feat,     // [N_NODES, D_FEAT]
    const float* __restrict__ adj,      // [N_NODES, N_NODES]
    const float* __restrict__ sims,     // [N_NODES, N_NODES]
    float* __restrict__ out)            // [BATCH, D_FEAT]
{
    const int b = blockIdx.x;
    const int t = threadIdx.x;  // 0..127

    __shared__ float w[K_NEIGH];
    __shared__ int   idx[K_NEIGH];

    if (t < K_NEIGH) {
        const int row = nodes[b];
        const int col = neigh_idx[(size_t)b * K_NEIGH + t];
        idx[t] = col;
        const size_t off = (size_t)row * N_NODES + (size_t)col;
        // two independent gathers; compiler can keep both in flight
        w[t] = adj[off] + sims[off];
    }
    __syncthreads();

    float denom = 0.0f;
    float acc   = 0.0f;
#pragma unroll
    for (int k = 0; k < K_NEIGH; ++k) {
        const float wk = w[k];                       // LDS broadcast, conflict-free
        denom += wk;
        acc   += wk * feat[(size_t)idx[k] * D_FEAT + t];
    }

    out[(size_t)b * D_FEAT + t] = acc / denom;
}

extern "C" void kernel_launch(void* const* d_in, const int* in_sizes, int n_in,
                              void* d_out, int out_size, void* d_ws, size_t ws_size,
                              hipStream_t stream) {
    const int*   nodes     = (const int*)d_in[0];
    const int*   neigh_idx = (const int*)d_in[1];
    const float* feat      = (const float*)d_in[2];
    const float* adj       = (const float*)d_in[3];
    const float* sims      = (const float*)d_in[4];
    float*       out       = (float*)d_out;

    mean_agg_kernel<<<BATCH, D_FEAT, 0, stream>>>(nodes, neigh_idx, feat, adj, sims, out);
}